// Round 15
// baseline (8322.467 us; speedup 1.0000x reference)
//
#include <hip/hip_runtime.h>

// Tanh RNN: B=64, S=2048, I=H=512, fp32 in/out.
//
// Round 15 = round 12 (verified, 6645 us rnn) + ONE mechanism change:
// the W-stream for kk12,13 moves from the LDS pipe to the TA/L2 pipe.
// Rationale: rounds 12<->13 showed the step is LDS-unit-throughput-bound
// (traffic x1.33 -> dur x1.25). Per CU/step: 208 wave-b128 LDS ops (~2500cy),
// of which 128 are W reads. kk12,13 (64KB, step-invariant, shared by all WGs)
// now come from a pre-swizzled global buffer: 16 coalesced b128 loads/wave
// issued at loop top (L2 latency hides under the kk0..11 MFMA phase).
// LDS ops drop to 144 (~1730cy); the 64KB/CU/step global stream (~1150cy on
// the TA pipe) overlaps. kk14,15 stay in LDS (8 chunks, 64KB).
//
// Structure (verified): 8 WGs, zero inter-WG comm; WG r owns batch rows
// r*8..+8, full j range. Weights: kk0..7 in AGPR (64 frags "+a"), kk8..11 in
// VGPR (32 frags "+v"), kk12,13 from L2, kk14,15 from LDS. h double-buffer
// [kk][lg][row] 16B entries. 4 waves, wave w owns j in [w*128,+128).
// LDS-only barrier per step. Split epilogue lo/hi (verified round 12).

typedef _Float16 half8 __attribute__((ext_vector_type(8)));
typedef _Float16 half4 __attribute__((ext_vector_type(4)));
typedef float f32x4 __attribute__((ext_vector_type(4)));
typedef unsigned long long u64;

#define S_SZ 2048
#define OUT1_OFF 67108864ull   // S*B*H floats

// workspace offsets (bytes)
#define XP_OFF    0ull              // 2048*64*512*2 = 134217728
#define WHH_OFF   134217728ull      // 524288
#define WIH_OFF   134742016ull      // 524288
#define BIAS_OFF  135266304ull      // 2048
#define WSWZ_OFF  135268352ull      // 65536 (swizzled kk12,13 frags)

#define WLDS_SZ   65536             // 8 chunks * 8192 B (kk 14..15 x lg 0..3)
#define HB_SZ     8192              // one h buffer: 16kk*4lg*8row*16B
#define SMEM_SZ   81920             // WLDS + 2*HB

__device__ __forceinline__ float fast_tanh(float x) {
    float a = exp2f(x * 2.8853900817779268f);
    return (a - 1.0f) * __builtin_amdgcn_rcpf(a + 1.0f);
}

__global__ void prep_kernel(const float* __restrict__ wih, const float* __restrict__ whh,
                            const float* __restrict__ bih, const float* __restrict__ bhh,
                            _Float16* __restrict__ wih16, _Float16* __restrict__ whh16,
                            float* __restrict__ bias)
{
    const int i = blockIdx.x * 256 + threadIdx.x;   // 1024 blocks -> 262144
    wih16[i] = (_Float16)wih[i];
    whh16[i] = (_Float16)whh[i];
    if (i < 512) bias[i] = bih[i] + bhh[i];
}

// swizzled kk12,13 weight frags for the global path:
// f16 offset = (((w*2+kkrel)*8+jt)*64 + lg*16 + l15) * 8
// -> per wave-instr (fixed kkrel,jt) lanes (lg,l15) read 1024B contiguous.
__global__ void wswz_kernel(const _Float16* __restrict__ whh16, _Float16* __restrict__ wswz)
{
    const int gid = blockIdx.x * 256 + threadIdx.x;   // 16 blocks -> 4096 frags
    const int l15 = gid & 15, lg = (gid >> 4) & 3, jt = (gid >> 6) & 7;
    const int kkrel = (gid >> 9) & 1, w = (gid >> 10) & 3;
    const int j = w * 128 + jt * 16 + l15;
    const int k = (12 + kkrel) * 32 + lg * 8;
    *reinterpret_cast<half8*>(wswz + (size_t)gid * 8) =
        *reinterpret_cast<const half8*>(whh16 + (size_t)j * 512 + k);
}

// ---------------- input projection GEMM (verified rounds 3-14) ----------------
__global__ __launch_bounds__(512, 1) void xproj_kernel(
    const float* __restrict__ inputs, const _Float16* __restrict__ wih16,
    const float* __restrict__ bias, _Float16* __restrict__ xp16)
{
    __shared__ _Float16 Alds[64 * 512];
    const int s = blockIdx.x;

    for (int idx = threadIdx.x; idx < 64 * 128; idx += 512) {
        const int row = idx >> 7, chunk = idx & 127;
        const float4 v = *reinterpret_cast<const float4*>(
            inputs + ((size_t)row * S_SZ + s) * 512 + chunk * 4);
        half4 hv;
        hv[0] = (_Float16)v.x; hv[1] = (_Float16)v.y;
        hv[2] = (_Float16)v.z; hv[3] = (_Float16)v.w;
        const int bc = (chunk * 8) ^ ((row & 7) << 4);
        *reinterpret_cast<half4*>(reinterpret_cast<char*>(Alds) + row * 1024 + bc) = hv;
    }
    __syncthreads();

    const int lane = threadIdx.x & 63, w = threadIdx.x >> 6;
    const int l15 = lane & 15, lg = lane >> 4;

    f32x4 acc[4][4];
    #pragma unroll
    for (int m = 0; m < 4; ++m)
        #pragma unroll
        for (int n = 0; n < 4; ++n)
            acc[m][n] = 0.0f;

    for (int kk = 0; kk < 16; ++kk) {
        half8 af[4], bf[4];
        #pragma unroll
        for (int m = 0; m < 4; ++m) {
            const int row = m * 16 + l15;
            const int bc = (kk * 64 + lg * 16) ^ ((row & 7) << 4);
            af[m] = *reinterpret_cast<const half8*>(
                reinterpret_cast<const char*>(Alds) + row * 1024 + bc);
        }
        #pragma unroll
        for (int n = 0; n < 4; ++n) {
            const int col = w * 64 + n * 16 + l15;
            bf[n] = *reinterpret_cast<const half8*>(wih16 + (size_t)col * 512 + kk * 32 + lg * 8);
        }
        #pragma unroll
        for (int m = 0; m < 4; ++m)
            #pragma unroll
            for (int n = 0; n < 4; ++n)
                acc[m][n] = __builtin_amdgcn_mfma_f32_16x16x32_f16(bf[n], af[m], acc[m][n], 0, 0, 0);
    }

    #pragma unroll
    for (int m = 0; m < 4; ++m) {
        const int brow = m * 16 + l15;
        #pragma unroll
        for (int n = 0; n < 4; ++n) {
            const int j0 = w * 64 + n * 16 + lg * 4;
            const float4 bv = *reinterpret_cast<const float4*>(bias + j0);
            half4 hv;
            hv[0] = (_Float16)(acc[m][n][0] + bv.x);
            hv[1] = (_Float16)(acc[m][n][1] + bv.y);
            hv[2] = (_Float16)(acc[m][n][2] + bv.z);
            hv[3] = (_Float16)(acc[m][n][3] + bv.w);
            *reinterpret_cast<half4*>(xp16 + ((size_t)s * 64 + brow) * 512 + j0) = hv;
        }
    }
}

// ---------------- recurrence ----------------
__global__ __launch_bounds__(256, 1) void rnn_step_kernel(
    const _Float16* __restrict__ whh16, const _Float16* __restrict__ xp16,
    const float* __restrict__ state, float* __restrict__ out,
    const _Float16* __restrict__ wswz)
{
    extern __shared__ __align__(16) char smem[];
    char* wlds = smem;                 // 8 chunks * 8192 (kk14,15)
    char* hb   = smem + WLDS_SZ;       // 2 * 8192

    const int r = blockIdx.x;          // 0..7: batch rows r*8..+8
    const int tid = threadIdx.x;
    const int lane = tid & 63, w = tid >> 6;   // 4 waves; wave w: j in [w*128, +128)
    const int l15 = lane & 15, lg = lane >> 4;
    const int row8 = l15 & 7;
    const bool hi = (l15 >= 8);        // epilogue half: jt 4..7

    // --- stage W-LDS (kk 14..15), linear: chunk c=(kk-14)*4+lgc, entry jj ---
    for (int idx = tid; idx < 8 * 512; idx += 256) {
        const int c = idx >> 9, jj = idx & 511;
        const int kk = 14 + (c >> 2), lgc = c & 3;
        *reinterpret_cast<half8*>(wlds + c * 8192 + jj * 16) =
            *reinterpret_cast<const half8*>(whh16 + (size_t)jj * 512 + kk * 32 + lgc * 8);
    }
    // --- stage h0 as [kk][lg][row] entries: h[row][kk*32+lg*8 .. +8] ---
    for (int idx = tid; idx < 512; idx += 256) {
        const int row = idx & 7, lgc = (idx >> 3) & 3, kk = idx >> 5;
        const float* sp = state + (size_t)(r * 8 + row) * 512 + kk * 32 + lgc * 8;
        const float4 v0 = *reinterpret_cast<const float4*>(sp);
        const float4 v1 = *reinterpret_cast<const float4*>(sp + 4);
        half8 hv;
        hv[0] = (_Float16)v0.x; hv[1] = (_Float16)v0.y;
        hv[2] = (_Float16)v0.z; hv[3] = (_Float16)v0.w;
        hv[4] = (_Float16)v1.x; hv[5] = (_Float16)v1.y;
        hv[6] = (_Float16)v1.z; hv[7] = (_Float16)v1.w;
        *reinterpret_cast<half8*>(hb + ((kk * 4 + lgc) * 8 + row) * 16) = hv;
    }

    // --- register weights: wa (kk0..7 -> AGPR) + wv (kk8..11 -> VGPR) ---
    half8 wa[64], wv[32];
    {
        const _Float16* wp = whh16 + (size_t)(w * 128 + l15) * 512 + lg * 8;
        #pragma unroll
        for (int jt = 0; jt < 8; ++jt) {
            #pragma unroll
            for (int kk = 0; kk < 8; ++kk)
                wa[jt * 8 + kk] = *reinterpret_cast<const half8*>(wp + jt * 16 * 512 + kk * 32);
            #pragma unroll
            for (int kk = 8; kk < 12; ++kk)
                wv[jt * 4 + kk - 8] = *reinterpret_cast<const half8*>(wp + jt * 16 * 512 + kk * 32);
        }
    }
    #pragma unroll
    for (int i = 0; i < 64; ++i) asm volatile("" : "+a"(wa[i]));
    #pragma unroll
    for (int i = 0; i < 32; ++i) asm volatile("" : "+v"(wv[i]));

    // per-lane base into wswz (f16 units); kkrel,jt offsets are compile-time
    const _Float16* wgbase = wswz + (size_t)w * 8192 + (lg * 16 + l15) * 8;

    // --- xp prefetch for t=0 (this lane's 4 jt only) ---
    u64 xq[4];
    {
        const _Float16* xpb = xp16 + (size_t)(r * 8 + row8) * 512
                              + w * 128 + (hi ? 64 : 0) + lg * 4;
        #pragma unroll
        for (int i = 0; i < 4; ++i)
            xq[i] = *reinterpret_cast<const u64*>(xpb + i * 16);
    }

    __syncthreads();   // staging barrier (full drain fine here, once)

    #pragma unroll 1
    for (int t = 0; t < S_SZ; ++t) {
        const char* hc = hb + (t & 1) * HB_SZ;
        char* hn = hb + ((t + 1) & 1) * HB_SZ;

        // ---- issue kk12,13 weight loads from L2 FIRST (latency hides under
        //      the kk0..11 MFMA phase). Opaque pin keeps the loads in-loop
        //      (prevents LICM hoisting 16 frags into registers we don't have).
        const _Float16* wg = wgbase;
        asm volatile("" : "+v"(wg));
        half8 wl[16];
        #pragma unroll
        for (int jt = 0; jt < 8; ++jt) {
            wl[jt]     = *reinterpret_cast<const half8*>(wg + jt * 512);        // kk12
            wl[8 + jt] = *reinterpret_cast<const half8*>(wg + 4096 + jt * 512); // kk13
        }

        f32x4 acc[8];
        #pragma unroll
        for (int jt = 0; jt < 8; ++jt) acc[jt] = 0.0f;

        // kk 0..7: AGPR-resident weights
        #pragma unroll
        for (int kk = 0; kk < 8; ++kk) {
            const half8 bf = *reinterpret_cast<const half8*>(
                hc + ((kk * 4 + lg) * 8 + row8) * 16);
            #pragma unroll
            for (int jt = 0; jt < 8; ++jt)
                acc[jt] = __builtin_amdgcn_mfma_f32_16x16x32_f16(
                    wa[jt * 8 + kk], bf, acc[jt], 0, 0, 0);
        }
        // kk 8..11: VGPR-resident weights
        #pragma unroll
        for (int kk = 8; kk < 12; ++kk) {
            const half8 bf = *reinterpret_cast<const half8*>(
                hc + ((kk * 4 + lg) * 8 + row8) * 16);
            #pragma unroll
            for (int jt = 0; jt < 8; ++jt)
                acc[jt] = __builtin_amdgcn_mfma_f32_16x16x32_f16(
                    wv[jt * 4 + kk - 8], bf, acc[jt], 0, 0, 0);
        }
        // kk 12..13: weights from L2 (wl; vmcnt wait auto via data dep)
        #pragma unroll
        for (int kk = 12; kk < 14; ++kk) {
            const half8 bf = *reinterpret_cast<const half8*>(
                hc + ((kk * 4 + lg) * 8 + row8) * 16);
            #pragma unroll
            for (int jt = 0; jt < 8; ++jt)
                acc[jt] = __builtin_amdgcn_mfma_f32_16x16x32_f16(
                    wl[(kk - 12) * 8 + jt], bf, acc[jt], 0, 0, 0);
        }
        // kk 14..15: weights from LDS
        #pragma unroll
        for (int kk = 14; kk < 16; ++kk) {
            const half8 bf = *reinterpret_cast<const half8*>(
                hc + ((kk * 4 + lg) * 8 + row8) * 16);
            const char* wc = wlds + ((kk - 14) * 4 + lg) * 8192;
            #pragma unroll
            for (int jt = 0; jt < 8; ++jt) {
                const half8 a = *reinterpret_cast<const half8*>(
                    wc + (w * 128 + jt * 16 + l15) * 16);
                acc[jt] = __builtin_amdgcn_mfma_f32_16x16x32_f16(a, bf, acc[jt], 0, 0, 0);
            }
        }

        // ---- split epilogue: lo lanes jt 0..3, hi lanes jt 4..7 ----
        const int rowi = r * 8 + row8;
        #pragma unroll
        for (int i = 0; i < 4; ++i) {
            const f32x4 a = hi ? acc[i + 4] : acc[i];   // static idx both arms
            union { _Float16 h[4]; u64 u; } xv, hp;
            xv.u = xq[i];
            f32x4 f;
            #pragma unroll
            for (int q = 0; q < 4; ++q) {
                f[q] = fast_tanh(a[q] + (float)xv.h[q]);
                hp.h[q] = (_Float16)f[q];
            }
            const int j0 = w * 128 + (hi ? 64 : 0) + i * 16 + lg * 4;  // lane-varying addr
            const int e = (((j0 >> 5) * 4 + ((j0 >> 3) & 3)) * 8 + row8);
            *reinterpret_cast<u64*>(hn + e * 16 + (lg & 1) * 8) = hp.u;
            *reinterpret_cast<f32x4*>(out + ((size_t)t * 64 + rowi) * 512 + j0) = f;
            if (t == S_SZ - 1) {
                #pragma unroll
                for (int q = 0; q < 4; ++q)
                    out[OUT1_OFF + (size_t)(j0 + q) * 64 + rowi] = f[q];
            }
        }

        // ---- xp reload for t+1 (vmcnt wait lands next iter, off critical path) ----
        if (t + 1 < S_SZ) {
            const _Float16* xpb = xp16 + ((size_t)(t + 1) * 64 + rowi) * 512
                                  + w * 128 + (hi ? 64 : 0) + lg * 4;
            #pragma unroll
            for (int i = 0; i < 4; ++i)
                xq[i] = *reinterpret_cast<const u64*>(xpb + i * 16);
        }

        // ---- LDS-only barrier: drain ds ops only; no vmcnt drain ----
        asm volatile("s_waitcnt lgkmcnt(0)" ::: "memory");
        __builtin_amdgcn_s_barrier();
    }
}

extern "C" void kernel_launch(void* const* d_in, const int* in_sizes, int n_in,
                              void* d_out, int out_size, void* d_ws, size_t ws_size,
                              hipStream_t stream)
{
    const float* inputs = (const float*)d_in[0];
    const float* state  = (const float*)d_in[1];
    const float* w_ih   = (const float*)d_in[2];
    const float* b_ih   = (const float*)d_in[3];
    const float* w_hh   = (const float*)d_in[4];
    const float* b_hh   = (const float*)d_in[5];
    float* out = (float*)d_out;
    char* ws = (char*)d_ws;

    _Float16* xp16  = (_Float16*)(ws + XP_OFF);
    _Float16* whh16 = (_Float16*)(ws + WHH_OFF);
    _Float16* wih16 = (_Float16*)(ws + WIH_OFF);
    float*    bias  = (float*)(ws + BIAS_OFF);
    _Float16* wswz  = (_Float16*)(ws + WSWZ_OFF);

    hipFuncSetAttribute((const void*)rnn_step_kernel,
                        hipFuncAttributeMaxDynamicSharedMemorySize, SMEM_SZ);

    prep_kernel<<<1024, 256, 0, stream>>>(w_ih, w_hh, b_ih, b_hh, wih16, whh16, bias);
    wswz_kernel<<<16, 256, 0, stream>>>(whh16, wswz);
    xproj_kernel<<<S_SZ, 512, 0, stream>>>(inputs, wih16, bias, xp16);
    rnn_step_kernel<<<8, 256, SMEM_SZ, stream>>>(whh16, xp16, state, out, wswz);
}

// Round 16
// 8290.706 us; speedup vs baseline: 1.0038x; 1.0038x over previous
//
#include <hip/hip_runtime.h>

// Tanh RNN: B=64, S=2048, I=H=512, fp32 in/out.
//
// Round 16 = round 12 (verified, 6645 us rnn) + ONE change:
// kk12,13 weights become PERMANENT register residents (wl[16] = 64 VGPR,
// loaded once pre-loop, "+v"-pinned), like wv. Rationale: R15 proved the
// transient wl copy fits at peak pressure (VGPR_Count=256, no spill) — and
// the weights are step-invariant, so a permanent copy costs the same peak.
// This removes R15's per-step global stream AND its vmcnt in-order trap
// (loads issued after stores force store-drain on the loads' wait).
// W-LDS shrinks to kk14,15 (8 chunks, 64 KB). Per-CU per-step LDS ops:
// 208 -> 144 (64 h-reads + 64 W-reads + 16 writes).
//
// Structure (verified): 8 WGs, zero inter-WG comm; WG r owns batch rows
// r*8..+8, full j range. Weights: kk0..7 AGPR (64 frags "+a"), kk8..13 VGPR
// (48 frags "+v"), kk14,15 LDS. h double-buffer [kk][lg][row] 16B entries.
// 4 waves, wave w owns j in [w*128,+128). LDS-only barrier per step.
// Split epilogue lo/hi (verified round 12).

typedef _Float16 half8 __attribute__((ext_vector_type(8)));
typedef _Float16 half4 __attribute__((ext_vector_type(4)));
typedef float f32x4 __attribute__((ext_vector_type(4)));
typedef unsigned long long u64;

#define S_SZ 2048
#define OUT1_OFF 67108864ull   // S*B*H floats

// workspace offsets (bytes)
#define XP_OFF    0ull              // 2048*64*512*2 = 134217728
#define WHH_OFF   134217728ull      // 524288
#define WIH_OFF   134742016ull      // 524288
#define BIAS_OFF  135266304ull      // 2048

#define WLDS_SZ   65536             // 8 chunks * 8192 B (kk 14..15 x lg 0..3)
#define HB_SZ     8192              // one h buffer: 16kk*4lg*8row*16B
#define SMEM_SZ   81920             // WLDS + 2*HB

__device__ __forceinline__ float fast_tanh(float x) {
    float a = exp2f(x * 2.8853900817779268f);
    return (a - 1.0f) * __builtin_amdgcn_rcpf(a + 1.0f);
}

__global__ void prep_kernel(const float* __restrict__ wih, const float* __restrict__ whh,
                            const float* __restrict__ bih, const float* __restrict__ bhh,
                            _Float16* __restrict__ wih16, _Float16* __restrict__ whh16,
                            float* __restrict__ bias)
{
    const int i = blockIdx.x * 256 + threadIdx.x;   // 1024 blocks -> 262144
    wih16[i] = (_Float16)wih[i];
    whh16[i] = (_Float16)whh[i];
    if (i < 512) bias[i] = bih[i] + bhh[i];
}

// ---------------- input projection GEMM (verified rounds 3-15) ----------------
__global__ __launch_bounds__(512, 1) void xproj_kernel(
    const float* __restrict__ inputs, const _Float16* __restrict__ wih16,
    const float* __restrict__ bias, _Float16* __restrict__ xp16)
{
    __shared__ _Float16 Alds[64 * 512];
    const int s = blockIdx.x;

    for (int idx = threadIdx.x; idx < 64 * 128; idx += 512) {
        const int row = idx >> 7, chunk = idx & 127;
        const float4 v = *reinterpret_cast<const float4*>(
            inputs + ((size_t)row * S_SZ + s) * 512 + chunk * 4);
        half4 hv;
        hv[0] = (_Float16)v.x; hv[1] = (_Float16)v.y;
        hv[2] = (_Float16)v.z; hv[3] = (_Float16)v.w;
        const int bc = (chunk * 8) ^ ((row & 7) << 4);
        *reinterpret_cast<half4*>(reinterpret_cast<char*>(Alds) + row * 1024 + bc) = hv;
    }
    __syncthreads();

    const int lane = threadIdx.x & 63, w = threadIdx.x >> 6;
    const int l15 = lane & 15, lg = lane >> 4;

    f32x4 acc[4][4];
    #pragma unroll
    for (int m = 0; m < 4; ++m)
        #pragma unroll
        for (int n = 0; n < 4; ++n)
            acc[m][n] = 0.0f;

    for (int kk = 0; kk < 16; ++kk) {
        half8 af[4], bf[4];
        #pragma unroll
        for (int m = 0; m < 4; ++m) {
            const int row = m * 16 + l15;
            const int bc = (kk * 64 + lg * 16) ^ ((row & 7) << 4);
            af[m] = *reinterpret_cast<const half8*>(
                reinterpret_cast<const char*>(Alds) + row * 1024 + bc);
        }
        #pragma unroll
        for (int n = 0; n < 4; ++n) {
            const int col = w * 64 + n * 16 + l15;
            bf[n] = *reinterpret_cast<const half8*>(wih16 + (size_t)col * 512 + kk * 32 + lg * 8);
        }
        #pragma unroll
        for (int m = 0; m < 4; ++m)
            #pragma unroll
            for (int n = 0; n < 4; ++n)
                acc[m][n] = __builtin_amdgcn_mfma_f32_16x16x32_f16(bf[n], af[m], acc[m][n], 0, 0, 0);
    }

    #pragma unroll
    for (int m = 0; m < 4; ++m) {
        const int brow = m * 16 + l15;
        #pragma unroll
        for (int n = 0; n < 4; ++n) {
            const int j0 = w * 64 + n * 16 + lg * 4;
            const float4 bv = *reinterpret_cast<const float4*>(bias + j0);
            half4 hv;
            hv[0] = (_Float16)(acc[m][n][0] + bv.x);
            hv[1] = (_Float16)(acc[m][n][1] + bv.y);
            hv[2] = (_Float16)(acc[m][n][2] + bv.z);
            hv[3] = (_Float16)(acc[m][n][3] + bv.w);
            *reinterpret_cast<half4*>(xp16 + ((size_t)s * 64 + brow) * 512 + j0) = hv;
        }
    }
}

// ---------------- recurrence ----------------
__global__ __launch_bounds__(256, 1) void rnn_step_kernel(
    const _Float16* __restrict__ whh16, const _Float16* __restrict__ xp16,
    const float* __restrict__ state, float* __restrict__ out)
{
    extern __shared__ __align__(16) char smem[];
    char* wlds = smem;                 // 8 chunks * 8192 (kk14,15)
    char* hb   = smem + WLDS_SZ;       // 2 * 8192

    const int r = blockIdx.x;          // 0..7: batch rows r*8..+8
    const int tid = threadIdx.x;
    const int lane = tid & 63, w = tid >> 6;   // 4 waves; wave w: j in [w*128, +128)
    const int l15 = lane & 15, lg = lane >> 4;
    const int row8 = l15 & 7;
    const bool hi = (l15 >= 8);        // epilogue half: jt 4..7

    // --- stage W-LDS (kk 14..15), linear: chunk c=(kk-14)*4+lgc, entry jj ---
    for (int idx = tid; idx < 8 * 512; idx += 256) {
        const int c = idx >> 9, jj = idx & 511;
        const int kk = 14 + (c >> 2), lgc = c & 3;
        *reinterpret_cast<half8*>(wlds + c * 8192 + jj * 16) =
            *reinterpret_cast<const half8*>(whh16 + (size_t)jj * 512 + kk * 32 + lgc * 8);
    }
    // --- stage h0 as [kk][lg][row] entries: h[row][kk*32+lg*8 .. +8] ---
    for (int idx = tid; idx < 512; idx += 256) {
        const int row = idx & 7, lgc = (idx >> 3) & 3, kk = idx >> 5;
        const float* sp = state + (size_t)(r * 8 + row) * 512 + kk * 32 + lgc * 8;
        const float4 v0 = *reinterpret_cast<const float4*>(sp);
        const float4 v1 = *reinterpret_cast<const float4*>(sp + 4);
        half8 hv;
        hv[0] = (_Float16)v0.x; hv[1] = (_Float16)v0.y;
        hv[2] = (_Float16)v0.z; hv[3] = (_Float16)v0.w;
        hv[4] = (_Float16)v1.x; hv[5] = (_Float16)v1.y;
        hv[6] = (_Float16)v1.z; hv[7] = (_Float16)v1.w;
        *reinterpret_cast<half8*>(hb + ((kk * 4 + lgc) * 8 + row) * 16) = hv;
    }

    // --- register weights: wa (kk0..7 -> AGPR), wv (kk8..11 -> VGPR),
    //     wl (kk12..13 -> VGPR, permanent: weights are step-invariant) ---
    half8 wa[64], wv[32], wl[16];
    {
        const _Float16* wp = whh16 + (size_t)(w * 128 + l15) * 512 + lg * 8;
        #pragma unroll
        for (int jt = 0; jt < 8; ++jt) {
            #pragma unroll
            for (int kk = 0; kk < 8; ++kk)
                wa[jt * 8 + kk] = *reinterpret_cast<const half8*>(wp + jt * 16 * 512 + kk * 32);
            #pragma unroll
            for (int kk = 8; kk < 12; ++kk)
                wv[jt * 4 + kk - 8] = *reinterpret_cast<const half8*>(wp + jt * 16 * 512 + kk * 32);
            #pragma unroll
            for (int kk = 12; kk < 14; ++kk)
                wl[jt * 2 + kk - 12] = *reinterpret_cast<const half8*>(wp + jt * 16 * 512 + kk * 32);
        }
    }
    // pin: opaque def blocks remat; "a"/"v" fixes the register class.
    #pragma unroll
    for (int i = 0; i < 64; ++i) asm volatile("" : "+a"(wa[i]));
    #pragma unroll
    for (int i = 0; i < 32; ++i) asm volatile("" : "+v"(wv[i]));
    #pragma unroll
    for (int i = 0; i < 16; ++i) asm volatile("" : "+v"(wl[i]));

    // --- xp prefetch for t=0 (this lane's 4 jt only) ---
    u64 xq[4];
    {
        const _Float16* xpb = xp16 + (size_t)(r * 8 + row8) * 512
                              + w * 128 + (hi ? 64 : 0) + lg * 4;
        #pragma unroll
        for (int i = 0; i < 4; ++i)
            xq[i] = *reinterpret_cast<const u64*>(xpb + i * 16);
    }

    __syncthreads();   // staging barrier (full drain fine here, once)

    #pragma unroll 1
    for (int t = 0; t < S_SZ; ++t) {
        const char* hc = hb + (t & 1) * HB_SZ;
        char* hn = hb + ((t + 1) & 1) * HB_SZ;

        f32x4 acc[8];
        #pragma unroll
        for (int jt = 0; jt < 8; ++jt) acc[jt] = 0.0f;

        // kk 0..7: AGPR-resident weights
        #pragma unroll
        for (int kk = 0; kk < 8; ++kk) {
            const half8 bf = *reinterpret_cast<const half8*>(
                hc + ((kk * 4 + lg) * 8 + row8) * 16);
            #pragma unroll
            for (int jt = 0; jt < 8; ++jt)
                acc[jt] = __builtin_amdgcn_mfma_f32_16x16x32_f16(
                    wa[jt * 8 + kk], bf, acc[jt], 0, 0, 0);
        }
        // kk 8..11: VGPR-resident weights
        #pragma unroll
        for (int kk = 8; kk < 12; ++kk) {
            const half8 bf = *reinterpret_cast<const half8*>(
                hc + ((kk * 4 + lg) * 8 + row8) * 16);
            #pragma unroll
            for (int jt = 0; jt < 8; ++jt)
                acc[jt] = __builtin_amdgcn_mfma_f32_16x16x32_f16(
                    wv[jt * 4 + kk - 8], bf, acc[jt], 0, 0, 0);
        }
        // kk 12..13: VGPR-resident weights (wl, permanent)
        #pragma unroll
        for (int kk = 12; kk < 14; ++kk) {
            const half8 bf = *reinterpret_cast<const half8*>(
                hc + ((kk * 4 + lg) * 8 + row8) * 16);
            #pragma unroll
            for (int jt = 0; jt < 8; ++jt)
                acc[jt] = __builtin_amdgcn_mfma_f32_16x16x32_f16(
                    wl[jt * 2 + kk - 12], bf, acc[jt], 0, 0, 0);
        }
        // kk 14..15: weights from LDS
        #pragma unroll
        for (int kk = 14; kk < 16; ++kk) {
            const half8 bf = *reinterpret_cast<const half8*>(
                hc + ((kk * 4 + lg) * 8 + row8) * 16);
            const char* wc = wlds + ((kk - 14) * 4 + lg) * 8192;
            #pragma unroll
            for (int jt = 0; jt < 8; ++jt) {
                const half8 a = *reinterpret_cast<const half8*>(
                    wc + (w * 128 + jt * 16 + l15) * 16);
                acc[jt] = __builtin_amdgcn_mfma_f32_16x16x32_f16(a, bf, acc[jt], 0, 0, 0);
            }
        }

        // ---- split epilogue: lo lanes jt 0..3, hi lanes jt 4..7 ----
        const int rowi = r * 8 + row8;
        #pragma unroll
        for (int i = 0; i < 4; ++i) {
            const f32x4 a = hi ? acc[i + 4] : acc[i];   // static idx both arms
            union { _Float16 h[4]; u64 u; } xv, hp;
            xv.u = xq[i];
            f32x4 f;
            #pragma unroll
            for (int q = 0; q < 4; ++q) {
                f[q] = fast_tanh(a[q] + (float)xv.h[q]);
                hp.h[q] = (_Float16)f[q];
            }
            const int j0 = w * 128 + (hi ? 64 : 0) + i * 16 + lg * 4;  // lane-varying addr
            const int e = (((j0 >> 5) * 4 + ((j0 >> 3) & 3)) * 8 + row8);
            *reinterpret_cast<u64*>(hn + e * 16 + (lg & 1) * 8) = hp.u;
            *reinterpret_cast<f32x4*>(out + ((size_t)t * 64 + rowi) * 512 + j0) = f;
            if (t == S_SZ - 1) {
                #pragma unroll
                for (int q = 0; q < 4; ++q)
                    out[OUT1_OFF + (size_t)(j0 + q) * 64 + rowi] = f[q];
            }
        }

        // ---- xp reload for t+1 (vmcnt wait lands next iter, off critical path) ----
        if (t + 1 < S_SZ) {
            const _Float16* xpb = xp16 + ((size_t)(t + 1) * 64 + rowi) * 512
                                  + w * 128 + (hi ? 64 : 0) + lg * 4;
            #pragma unroll
            for (int i = 0; i < 4; ++i)
                xq[i] = *reinterpret_cast<const u64*>(xpb + i * 16);
        }

        // ---- LDS-only barrier: drain ds ops only; no vmcnt drain ----
        asm volatile("s_waitcnt lgkmcnt(0)" ::: "memory");
        __builtin_amdgcn_s_barrier();
    }
}

extern "C" void kernel_launch(void* const* d_in, const int* in_sizes, int n_in,
                              void* d_out, int out_size, void* d_ws, size_t ws_size,
                              hipStream_t stream)
{
    const float* inputs = (const float*)d_in[0];
    const float* state  = (const float*)d_in[1];
    const float* w_ih   = (const float*)d_in[2];
    const float* b_ih   = (const float*)d_in[3];
    const float* w_hh   = (const float*)d_in[4];
    const float* b_hh   = (const float*)d_in[5];
    float* out = (float*)d_out;
    char* ws = (char*)d_ws;

    _Float16* xp16  = (_Float16*)(ws + XP_OFF);
    _Float16* whh16 = (_Float16*)(ws + WHH_OFF);
    _Float16* wih16 = (_Float16*)(ws + WIH_OFF);
    float*    bias  = (float*)(ws + BIAS_OFF);

    hipFuncSetAttribute((const void*)rnn_step_kernel,
                        hipFuncAttributeMaxDynamicSharedMemorySize, SMEM_SZ);

    prep_kernel<<<1024, 256, 0, stream>>>(w_ih, w_hh, b_ih, b_hh, wih16, whh16, bias);
    xproj_kernel<<<S_SZ, 512, 0, stream>>>(inputs, wih16, bias, xp16);
    rnn_step_kernel<<<8, 256, SMEM_SZ, stream>>>(whh16, xp16, state, out);
}